// Round 5
// baseline (1580.579 us; speedup 1.0000x reference)
//
#include <hip/hip_runtime.h>
#include <math.h>

#define BB 64
#define DD 128
#define NN 400
#define MM 50
#define HH 8
#define KDIM 16
#define NC 4
#define KW 7
#define SP 52   // pitched S row

#define SZ_C (BB * DD * NN)   // 3,276,800
#define SZ_Q (BB * DD * MM)   //   409,600
#define SSTAT (BB * NN + BB * MM)

// ---------------- canonical weight transpose: Wcan[m][d][e] ----------------
__global__ void k_transposeW(const float* __restrict__ pw_w, const float* __restrict__ Wo,
                             const float* __restrict__ Wfc, const float* __restrict__ Wq,
                             const float* __restrict__ Wk, const float* __restrict__ Wv,
                             float* __restrict__ Wcan) {
  int idx = blockIdx.x * 256 + threadIdx.x;
  if (idx >= 9 * 16384) return;
  int m = idx >> 14;
  int r = idx & 16383;
  int d = r >> 7, e = r & 127;
  float v;
  if (m < 4) v = pw_w[m * 16384 + e * 128 + d];
  else if (m == 4) v = Wo[d * 128 + e];
  else if (m == 5) v = Wfc[e * 128 + d];
  else {
    const float* W = (m == 6) ? Wq : (m == 7) ? Wk : Wv;
    v = W[((e >> 4) * 128 + d) * 16 + (e & 15)];
  }
  Wcan[idx] = v;
}

// ---------------- position encoding add ----------------
__global__ void k_pe(const float* __restrict__ xC, const float* __restrict__ xQ,
                     float* __restrict__ yC, float* __restrict__ yQ) {
  int idx = blockIdx.x * 256 + threadIdx.x;
  const float* x; float* y; int L, id2;
  if (idx < SZ_C) { x = xC; y = yC; L = NN; id2 = idx; }
  else if (idx < SZ_C + SZ_Q) { x = xQ; y = yQ; L = MM; id2 = idx - SZ_C; }
  else return;
  int l = id2 % L;
  int d = (id2 / L) % DD;
  int de = d & ~1;
  float freq = __expf((float)de * (-9.210340371976184f / 128.0f));
  float phase = (d & 1) ? 1.5707963267948966f : 0.0f;
  y[id2] = x[id2] + sinf((float)l * freq + phase);
}

// ---------------- LN stats ----------------
__global__ void k_lnstats(const float* __restrict__ xC, const float* __restrict__ xQ,
                          float* __restrict__ mu, float* __restrict__ inv) {
  int blk = blockIdx.x;
  const float* x; int L, lt, b, soff;
  if (blk < 448) { b = blk / 7; lt = blk % 7; x = xC; L = NN; soff = 0; }
  else { b = blk - 448; lt = 0; x = xQ; L = MM; soff = BB * NN; }
  int ll = threadIdx.x & 63;
  int dq = threadIdx.x >> 6;
  int l = lt * 64 + ll;
  __shared__ float s_sum[4][64], s_sq[4][64];
  float sum = 0.f, sq = 0.f;
  const float* px = x + (size_t)b * DD * L + l;
  if (l < L) {
    for (int d = dq * 32; d < dq * 32 + 32; ++d) {
      float v = px[(size_t)d * L];
      sum += v; sq += v * v;
    }
  }
  s_sum[dq][ll] = sum; s_sq[dq][ll] = sq;
  __syncthreads();
  if (dq == 0 && l < L) {
    float ts = s_sum[0][ll] + s_sum[1][ll] + s_sum[2][ll] + s_sum[3][ll];
    float tq = s_sq[0][ll] + s_sq[1][ll] + s_sq[2][ll] + s_sq[3][ll];
    float m = ts * (1.0f / 128.0f);
    float var = (tq - 128.0f * m * m) * (1.0f / 127.0f);
    float sd = sqrtf(fmaxf(var, 0.f));
    mu[soff + b * L + l] = m;
    inv[soff + b * L + l] = 1.0f / (sd + 1e-6f);
  }
}

__device__ inline void mma16(float4 wv, float4 xv, float acc[4][4]) {
  float wa[4] = {wv.x, wv.y, wv.z, wv.w};
  float xa[4] = {xv.x, xv.y, xv.z, xv.w};
  #pragma unroll
  for (int i = 0; i < 4; ++i)
    #pragma unroll
    for (int j = 0; j < 4; ++j) acc[i][j] += wa[i] * xa[j];
}

// ---------------- fused LN + depthwise conv + pointwise GEMM + relu + residual ----------
__global__ __launch_bounds__(256) void k_gemmconv(
    const float* __restrict__ xC, const float* __restrict__ xQ,
    float* __restrict__ yC, float* __restrict__ yQ,
    const float* __restrict__ w7, const float* __restrict__ dwb,
    const float* __restrict__ Wc, const float* __restrict__ pwb,
    const float* __restrict__ mu, const float* __restrict__ inv,
    const float* __restrict__ g, const float* __restrict__ beta) {
  int b = blockIdx.x >> 4, t = blockIdx.x & 15;
  const float* x; float* y; int L, l0, et, soff;
  if (t < 14) { x = xC; y = yC; L = NN; l0 = (t >> 1) * 64; et = t & 1; soff = 0; }
  else { x = xQ; y = yQ; L = MM; l0 = 0; et = t - 14; soff = BB * NN; }
  int e0b = et * 64;
  __shared__ float Xr[32][72];
  __shared__ float Xc[32][68];
  __shared__ float Wl[32][64];
  int tid = threadIdx.x;
  float acc[4][4] = {};
  const float* xb = x + (size_t)b * DD * L;
  const float* pmu = mu + soff + b * L;
  const float* pin = inv + soff + b * L;
  for (int kc = 0; kc < 4; ++kc) {
    int d0 = kc * 32;
    #pragma unroll
    for (int it = 0; it < 9; ++it) {
      int idx = it * 256 + tid;
      int d = idx / 72, lx = idx % 72;
      float v = 0.f;
      int gl = l0 - 3 + lx;
      if (lx < 70 && gl >= 0 && gl < L) {
        v = xb[(size_t)(d0 + d) * L + gl];
        v = g[d0 + d] * (v - pmu[gl]) * pin[gl] + beta[d0 + d];
      }
      Xr[d][lx] = v;
    }
    #pragma unroll
    for (int it = 0; it < 8; ++it) {
      int idx = it * 256 + tid;
      int k = idx >> 6, e = idx & 63;
      Wl[k][e] = Wc[(size_t)(d0 + k) * DD + e0b + e];
    }
    __syncthreads();
    #pragma unroll
    for (int it = 0; it < 8; ++it) {
      int idx = it * 256 + tid;
      int d = idx >> 6, l = idx & 63;
      const float* wr = w7 + (size_t)(d0 + d) * KW;
      float a = dwb[d0 + d];
      #pragma unroll
      for (int k = 0; k < 7; ++k) a += wr[k] * Xr[d][l + k];
      Xc[d][l] = a;
    }
    __syncthreads();
    int te = (tid >> 4) * 4, tl = (tid & 15) * 4;
    for (int k = 0; k < 32; ++k) {
      float4 wv = *(const float4*)&Wl[k][te];
      float4 xv = *(const float4*)&Xc[k][tl];
      mma16(wv, xv, acc);
    }
    __syncthreads();
  }
  int te = e0b + (tid >> 4) * 4, tl = l0 + (tid & 15) * 4;
  #pragma unroll
  for (int i = 0; i < 4; ++i) {
    int e = te + i;
    float bi = pwb[e];
    float* po = y + ((size_t)b * DD + e) * L;
    const float* pr = x + ((size_t)b * DD + e) * L;
    if (L == NN && tl + 3 < NN) {
      float4 rv = *(const float4*)&pr[tl];
      float4 ov;
      ov.x = fmaxf(acc[i][0] + bi, 0.f) + rv.x;
      ov.y = fmaxf(acc[i][1] + bi, 0.f) + rv.y;
      ov.z = fmaxf(acc[i][2] + bi, 0.f) + rv.z;
      ov.w = fmaxf(acc[i][3] + bi, 0.f) + rv.w;
      *(float4*)&po[tl] = ov;
    } else {
      #pragma unroll
      for (int j = 0; j < 4; ++j) {
        int l = tl + j;
        if (l < L) po[l] = fmaxf(acc[i][j] + bi, 0.f) + pr[l];
      }
    }
  }
}

// ---------------- plain 128x128 GEMM (Wo / FC), +bias +residual ----------------
template <int LNF>
__global__ __launch_bounds__(256) void k_gemmB(
    const float* __restrict__ xC, const float* __restrict__ xQ,
    const float* __restrict__ resC, const float* __restrict__ resQ,
    float* __restrict__ yC, float* __restrict__ yQ,
    const float* __restrict__ Wc, const float* __restrict__ bias,
    const float* __restrict__ mu, const float* __restrict__ inv,
    const float* __restrict__ g, const float* __restrict__ beta) {
  int b = blockIdx.x >> 4, t = blockIdx.x & 15;
  const float *x, *res; float* y; int L, l0, et, soff;
  if (t < 14) { x = xC; res = resC; y = yC; L = NN; l0 = (t >> 1) * 64; et = t & 1; soff = 0; }
  else { x = xQ; res = resQ; y = yQ; L = MM; l0 = 0; et = t - 14; soff = BB * NN; }
  int e0b = et * 64;
  __shared__ float Xl[32][68];
  __shared__ float Wl[32][64];
  int tid = threadIdx.x;
  float acc[4][4] = {};
  const float* xb = x + (size_t)b * DD * L;
  const float* pmu = mu + soff + b * L;
  const float* pin = inv + soff + b * L;
  for (int kc = 0; kc < 4; ++kc) {
    int d0 = kc * 32;
    #pragma unroll
    for (int it = 0; it < 8; ++it) {
      int idx = it * 256 + tid;
      int k = idx >> 6, l = idx & 63;
      float v = 0.f;
      int gl = l0 + l;
      if (gl < L) {
        v = xb[(size_t)(d0 + k) * L + gl];
        if (LNF) v = g[d0 + k] * (v - pmu[gl]) * pin[gl] + beta[d0 + k];
      }
      Xl[k][l] = v;
    }
    #pragma unroll
    for (int it = 0; it < 8; ++it) {
      int idx = it * 256 + tid;
      int k = idx >> 6, e = idx & 63;
      Wl[k][e] = Wc[(size_t)(d0 + k) * DD + e0b + e];
    }
    __syncthreads();
    int te = (tid >> 4) * 4, tl = (tid & 15) * 4;
    for (int k = 0; k < 32; ++k) {
      float4 wv = *(const float4*)&Wl[k][te];
      float4 xv = *(const float4*)&Xl[k][tl];
      mma16(wv, xv, acc);
    }
    __syncthreads();
  }
  int te = e0b + (tid >> 4) * 4, tl = l0 + (tid & 15) * 4;
  #pragma unroll
  for (int i = 0; i < 4; ++i) {
    int e = te + i;
    float bi = bias[e];
    float* po = y + ((size_t)b * DD + e) * L;
    const float* pr = res + ((size_t)b * DD + e) * L;
    if (L == NN && tl + 3 < NN) {
      float4 rv = *(const float4*)&pr[tl];
      float4 ov;
      ov.x = acc[i][0] + bi + rv.x;
      ov.y = acc[i][1] + bi + rv.y;
      ov.z = acc[i][2] + bi + rv.z;
      ov.w = acc[i][3] + bi + rv.w;
      *(float4*)&po[tl] = ov;
    } else {
      #pragma unroll
      for (int j = 0; j < 4; ++j) {
        int l = tl + j;
        if (l < L) po[l] = acc[i][j] + bi + pr[l];
      }
    }
  }
}

// ---------------- QKV GEMM: one launch; Q -> plane layout, K/V -> [bh][l][16] ----------
__global__ __launch_bounds__(256) void k_gemmA(
    const float* __restrict__ xC, const float* __restrict__ xQ,
    float* __restrict__ qC, float* __restrict__ qQ,
    float* __restrict__ ktC, float* __restrict__ ktQ,
    float* __restrict__ vtC, float* __restrict__ vtQ,
    const float* __restrict__ Wcan6,
    const float* __restrict__ bq, const float* __restrict__ bk, const float* __restrict__ bv,
    const float* __restrict__ mu, const float* __restrict__ inv,
    const float* __restrict__ g, const float* __restrict__ beta) {
  int b = blockIdx.x / 48, t = blockIdx.x % 48;
  const float* x; float *qp, *ktp, *vtp; int L, l0, e6, soff;
  if (t < 42) { x = xC; qp = qC; ktp = ktC; vtp = vtC; L = NN; l0 = (t / 6) * 64; e6 = t % 6; soff = 0; }
  else { x = xQ; qp = qQ; ktp = ktQ; vtp = vtQ; L = MM; l0 = 0; e6 = t - 42; soff = BB * NN; }
  int w = e6 >> 1, et = e6 & 1, e0b = et * 64;
  const float* Wc = Wcan6 + (size_t)w * 16384;
  const float* bias = (w == 0) ? bq : (w == 1) ? bk : bv;
  __shared__ float Xl[32][68];
  __shared__ float Wl[32][64];
  int tid = threadIdx.x;
  float acc[4][4] = {};
  const float* xb = x + (size_t)b * DD * L;
  const float* pmu = mu + soff + b * L;
  const float* pin = inv + soff + b * L;
  for (int kc = 0; kc < 4; ++kc) {
    int d0 = kc * 32;
    #pragma unroll
    for (int it = 0; it < 8; ++it) {
      int idx = it * 256 + tid;
      int k = idx >> 6, l = idx & 63;
      float v = 0.f;
      int gl = l0 + l;
      if (gl < L) {
        v = xb[(size_t)(d0 + k) * L + gl];
        v = g[d0 + k] * (v - pmu[gl]) * pin[gl] + beta[d0 + k];
      }
      Xl[k][l] = v;
    }
    #pragma unroll
    for (int it = 0; it < 8; ++it) {
      int idx = it * 256 + tid;
      int k = idx >> 6, e = idx & 63;
      Wl[k][e] = Wc[(size_t)(d0 + k) * DD + e0b + e];
    }
    __syncthreads();
    int te = (tid >> 4) * 4, tl = (tid & 15) * 4;
    for (int k = 0; k < 32; ++k) {
      float4 wv = *(const float4*)&Wl[k][te];
      float4 xv = *(const float4*)&Xl[k][tl];
      mma16(wv, xv, acc);
    }
    __syncthreads();
  }
  int te = e0b + (tid >> 4) * 4, tl = l0 + (tid & 15) * 4;
  if (w == 0) {
    #pragma unroll
    for (int i = 0; i < 4; ++i) {
      int e = te + i;
      float bi = bias[e];
      float* po = qp + ((size_t)b * DD + e) * L;
      #pragma unroll
      for (int j = 0; j < 4; ++j) {
        int l = tl + j;
        if (l < L) po[l] = acc[i][j] + bi;
      }
    }
  } else {
    float* dst = (w == 1) ? ktp : vtp;
    int h = te >> 4, t0 = te & 15;
    float b0 = bias[te], b1 = bias[te + 1], b2 = bias[te + 2], b3 = bias[te + 3];
    size_t bhL = (size_t)(b * 8 + h) * L;
    #pragma unroll
    for (int j = 0; j < 4; ++j) {
      int l = tl + j;
      if (l < L) {
        float4 val;
        val.x = acc[0][j] + b0;
        val.y = acc[1][j] + b1;
        val.z = acc[2][j] + b2;
        val.w = acc[3][j] + b3;
        *(float4*)&dst[(bhL + l) * 16 + t0] = val;
      }
    }
  }
}

// ---------------- register-tiled flash attention ----------------
// 256 thr = 16 ti x 16 tj; thread owns i = i0+ti*2+{0,1}, keys j = j0+tj*4+{0..3}.
// K/V in LDS [L][16]; per-lane distinct rows -> no broadcast waste.
// ctx: 512 bh x 13 i-tiles(32) = 6656 blocks; question: 512 bh x 2 = 1024.
__global__ __launch_bounds__(256) void k_attn4(
    const float* __restrict__ qC, const float* __restrict__ ktC, const float* __restrict__ vtC,
    const float* __restrict__ qQ, const float* __restrict__ ktQ, const float* __restrict__ vtQ,
    const float* __restrict__ cmask, const float* __restrict__ qmask,
    float* __restrict__ oC, float* __restrict__ oQ) {
  int blk = blockIdx.x;
  const float *qp, *kt, *vt, *mk; float* op; int L, b, h, i0;
  if (blk < 6656) {
    int bh = blk / 13, it = blk % 13;
    b = bh >> 3; h = bh & 7; i0 = it * 32;
    qp = qC; kt = ktC; vt = vtC; mk = cmask; op = oC; L = NN;
  } else {
    int r = blk - 6656; int bh = r >> 1; int it = r & 1;
    b = bh >> 3; h = bh & 7; i0 = it * 32;
    qp = qQ; kt = ktQ; vt = vtQ; mk = qmask; op = oQ; L = MM;
  }
  __shared__ float Sh[13200];   // Kl 6400 | Vl 6400 | Pen 400  (52.8KB, 3 blk/CU)
  float* Kl = Sh;
  float* Vl = Sh + 6400;
  float* Pen = Sh + 12800;
  int tid = threadIdx.x;
  size_t kvbase = (size_t)(b * 8 + h) * L * 16;
  const float4* kg = (const float4*)(kt + kvbase);
  const float4* vg = (const float4*)(vt + kvbase);
  float4* K4 = (float4*)Kl;
  float4* V4 = (float4*)Vl;
  for (int x = tid; x < L * 4; x += 256) { K4[x] = kg[x]; V4[x] = vg[x]; }
  for (int j = tid; j < L; j += 256) Pen[j] = -1e30f * (1.0f - mk[b * L + j]);
  __syncthreads();

  int ti = tid >> 4, tj = tid & 15;
  int iA = i0 + ti * 2, iB = iA + 1;
  bool aA = iA < L, aB = iB < L;
  size_t qbase = ((size_t)b * DD + h * 16) * L;
  float q0[16], q1[16];
  #pragma unroll
  for (int t = 0; t < 16; ++t) {
    q0[t] = aA ? qp[qbase + (size_t)t * L + iA] : 0.f;
    q1[t] = aB ? qp[qbase + (size_t)t * L + iB] : 0.f;
  }
  float m0r = -1e30f, m1r = -1e30f, l0r = 0.f, l1r = 0.f;
  float O0[16] = {}, O1[16] = {};
  int njt = (L + 63) >> 6;
  for (int jt = 0; jt < njt; ++jt) {
    int jb = jt * 64 + tj * 4;
    float s0[4], s1[4];
    #pragma unroll
    for (int jj = 0; jj < 4; ++jj) {
      int j = jb + jj;
      int jc = j < L ? j : L - 1;
      const float4* kr = (const float4*)&Kl[jc * 16];
      float4 k0 = kr[0], k1 = kr[1], k2 = kr[2], k3 = kr[3];
      float d0 = q0[0]*k0.x + q0[1]*k0.y + q0[2]*k0.z + q0[3]*k0.w
               + q0[4]*k1.x + q0[5]*k1.y + q0[6]*k1.z + q0[7]*k1.w
               + q0[8]*k2.x + q0[9]*k2.y + q0[10]*k2.z + q0[11]*k2.w
               + q0[12]*k3.x + q0[13]*k3.y + q0[14]*k3.z + q0[15]*k3.w;
      float d1 = q1[0]*k0.x + q1[1]*k0.y + q1[2]*k0.z + q1[3]*k0.w
               + q1[4]*k1.x + q1[5]*k1.y + q1[6]*k1.z + q1[7]*k1.w
               + q1[8]*k2.x + q1[9]*k2.y + q1[10]*k2.z + q1[11]*k2.w
               + q1[12]*k3.x + q1[13]*k3.y + q1[14]*k3.z + q1[15]*k3.w;
      float pen = (j < L) ? Pen[j] : -1e30f;
      s0[jj] = d0 * 0.25f + pen;
      s1[jj] = d1 * 0.25f + pen;
    }
    float t0 = fmaxf(fmaxf(s0[0], s0[1]), fmaxf(s0[2], s0[3]));
    float t1 = fmaxf(fmaxf(s1[0], s1[1]), fmaxf(s1[2], s1[3]));
    #pragma unroll
    for (int off = 1; off < 16; off <<= 1) {
      t0 = fmaxf(t0, __shfl_xor(t0, off));
      t1 = fmaxf(t1, __shfl_xor(t1, off));
    }
    float nm0 = fmaxf(m0r, t0), nm1 = fmaxf(m1r, t1);
    float sc0 = __expf(m0r - nm0), sc1 = __expf(m1r - nm1);
    l0r *= sc0; l1r *= sc1;
    #pragma unroll
    for (int t = 0; t < 16; ++t) { O0[t] *= sc0; O1[t] *= sc1; }
    m0r = nm0; m1r = nm1;
    #pragma unroll
    for (int jj = 0; jj < 4; ++jj) {
      int j = jb + jj;
      int jc = j < L ? j : L - 1;
      float p0 = __expf(s0[jj] - m0r);
      float p1 = __expf(s1[jj] - m1r);
      l0r += p0; l1r += p1;
      const float4* vr = (const float4*)&Vl[jc * 16];
      float4 v0 = vr[0], v1 = vr[1], v2 = vr[2], v3 = vr[3];
      O0[0] += p0*v0.x;  O0[1] += p0*v0.y;  O0[2] += p0*v0.z;  O0[3] += p0*v0.w;
      O0[4] += p0*v1.x;  O0[5] += p0*v1.y;  O0[6] += p0*v1.z;  O0[7] += p0*v1.w;
      O0[8] += p0*v2.x;  O0[9] += p0*v2.y;  O0[10] += p0*v2.z; O0[11] += p0*v2.w;
      O0[12] += p0*v3.x; O0[13] += p0*v3.y; O0[14] += p0*v3.z; O0[15] += p0*v3.w;
      O1[0] += p1*v0.x;  O1[1] += p1*v0.y;  O1[2] += p1*v0.z;  O1[3] += p1*v0.w;
      O1[4] += p1*v1.x;  O1[5] += p1*v1.y;  O1[6] += p1*v1.z;  O1[7] += p1*v1.w;
      O1[8] += p1*v2.x;  O1[9] += p1*v2.y;  O1[10] += p1*v2.z; O1[11] += p1*v2.w;
      O1[12] += p1*v3.x; O1[13] += p1*v3.y; O1[14] += p1*v3.z; O1[15] += p1*v3.w;
    }
  }
  // ---- cross-tj reduction via LDS (pad-17 stride), then write ----
  __syncthreads();  // everyone done with Kl/Vl
  #pragma unroll
  for (int t = 0; t < 16; ++t) {
    Sh[((0 * 16 + ti) * 16 + t) * 17 + tj] = O0[t];
    Sh[((1 * 16 + ti) * 16 + t) * 17 + tj] = O1[t];
  }
  Sh[8704 + (ti * 2 + 0) * 17 + tj] = l0r;
  Sh[8704 + (ti * 2 + 1) * 17 + tj] = l1r;
  __syncthreads();
  #pragma unroll
  for (int r = 0; r < 2; ++r) {
    int o = tid * 2 + r;
    int t = o & 15, ti2 = (o >> 4) & 15, ii = o >> 8;
    int i = i0 + ti2 * 2 + ii;
    if (i < L) {
      float s = 0.f, ls = 0.f;
      #pragma unroll
      for (int k = 0; k < 16; ++k) {
        s += Sh[o * 17 + k];
        ls += Sh[8704 + (ti2 * 2 + ii) * 17 + k];
      }
      op[qbase + (size_t)t * L + i] = s / ls;
    }
  }
}

// ---------------- [B,D,L] -> [B,L,D] transpose ----------------
__global__ void k_transpose(const float* __restrict__ X, float* __restrict__ Y,
                            int L, int total) {
  int idx = blockIdx.x * 256 + threadIdx.x;
  if (idx >= total) return;
  int d = idx % DD;
  int l = (idx / DD) % L;
  int b = idx / (DD * L);
  Y[idx] = X[((size_t)b * DD + d) * L + l];
}

// ---------------- dot over D: out[b,l] = sum_d X[b,d,l]*w[d] ----------------
__global__ void k_dotD(const float* __restrict__ X, const float* __restrict__ w,
                       float* __restrict__ out, int L, int total) {
  int idx = blockIdx.x * 256 + threadIdx.x;
  if (idx >= total) return;
  int l = idx % L;
  int b = idx / L;
  const float* px = X + (size_t)b * DD * L + l;
  float acc = 0.f;
  for (int d = 0; d < DD; ++d) acc += px[(size_t)d * L] * w[d];
  out[idx] = acc;
}

// ---------------- S trilinear, tiled GEMM; S pitch SP ----------------
__global__ __launch_bounds__(256) void k_S(
    const float* __restrict__ C2, const float* __restrict__ Q2,
    const float* __restrict__ cd, const float* __restrict__ qd,
    const float* __restrict__ wm, const float* __restrict__ cqb,
    float* __restrict__ S) {
  int b = blockIdx.x / 7, nt = blockIdx.x % 7;
  int n0 = nt * 64;
  __shared__ float Qw[DD][64];
  __shared__ float Cl[32][68];
  int tid = threadIdx.x;
  #pragma unroll
  for (int it = 0; it < 25; ++it) {
    int idx = it * 256 + tid;
    int m = idx >> 7, d = idx & 127;
    Qw[d][m] = Q2[((size_t)b * MM + m) * DD + d] * wm[d];
  }
  for (int it = 0; it < 7; ++it) {
    int idx = it * 256 + tid;
    if (idx < 128 * 14) Qw[idx / 14][50 + idx % 14] = 0.f;
  }
  float acc[4][4] = {};
  const float* c2b = C2 + (size_t)b * NN * DD;
  for (int kc = 0; kc < 4; ++kc) {
    int d0 = kc * 32;
    #pragma unroll
    for (int it = 0; it < 8; ++it) {
      int idx = it * 256 + tid;
      int n = idx >> 5, k = idx & 31;
      int gn = n0 + n;
      Cl[k][n] = (gn < NN) ? c2b[(size_t)gn * DD + d0 + k] : 0.f;
    }
    __syncthreads();
    int tm = (tid >> 4) * 4, tn = (tid & 15) * 4;
    for (int k = 0; k < 32; ++k) {
      float4 qv = *(const float4*)&Qw[d0 + k][tm];
      float4 cv = *(const float4*)&Cl[k][tn];
      mma16(qv, cv, acc);
    }
    __syncthreads();
  }
  int tm = (tid >> 4) * 4, tn0 = n0 + (tid & 15) * 4;
  if (tm < MM) {
    float qv[4];
    #pragma unroll
    for (int i = 0; i < 4; ++i) qv[i] = (tm + i < MM) ? qd[b * MM + tm + i] : 0.f;
    float bias0 = cqb[0];
    #pragma unroll
    for (int j = 0; j < 4; ++j) {
      int n = tn0 + j;
      if (n < NN) {
        float cdv = cd[b * NN + n] + bias0;
        float4 val;
        val.x = acc[0][j] + qv[0] + cdv;
        val.y = acc[1][j] + qv[1] + cdv;
        val.z = acc[2][j] + qv[2] + cdv;
        val.w = acc[3][j] + qv[3] + cdv;
        *(float4*)&S[((size_t)b * NN + n) * SP + tm] = val;
      }
    }
  }
}

// ---------------- softmax over n (col) -> Sc; pitch SP ----------------
__global__ void k_smax_col(const float* __restrict__ S, const float* __restrict__ cmask,
                           float* __restrict__ Sc) {
  int b = blockIdx.x / MM;
  int mcol = blockIdx.x % MM;
  int tid = threadIdx.x;
  float vals[7];
  float mx = -1e30f;
  #pragma unroll
  for (int c = 0; c < 7; ++c) {
    int n = tid + c * 64;
    float s = -1e30f;
    if (n < NN)
      s = S[((size_t)b * NN + n) * SP + mcol] - 1e30f * (1.0f - cmask[b * NN + n]);
    vals[c] = s;
    mx = fmaxf(mx, s);
  }
  #pragma unroll
  for (int off = 1; off < 64; off <<= 1) mx = fmaxf(mx, __shfl_xor(mx, off));
  float sum = 0.f;
  #pragma unroll
  for (int c = 0; c < 7; ++c) { vals[c] = __expf(vals[c] - mx); sum += vals[c]; }
  #pragma unroll
  for (int off = 1; off < 64; off <<= 1) sum += __shfl_xor(sum, off);
  float inv = 1.0f / sum;
  #pragma unroll
  for (int c = 0; c < 7; ++c) {
    int n = tid + c * 64;
    if (n < NN) Sc[((size_t)b * NN + n) * SP + mcol] = vals[c] * inv;
  }
}

// ---------------- softmax over m (row), in-place; pitch SP ----------------
__global__ void k_smax_row(float* __restrict__ S, const float* __restrict__ qmask) {
  int bn = blockIdx.x;
  int b = bn / NN;
  int tid = threadIdx.x;
  float s = -1e30f;
  if (tid < MM)
    s = S[(size_t)bn * SP + tid] - 1e30f * (1.0f - qmask[b * MM + tid]);
  float mx = s;
  #pragma unroll
  for (int off = 1; off < 64; off <<= 1) mx = fmaxf(mx, __shfl_xor(mx, off));
  float e = (tid < MM) ? __expf(s - mx) : 0.f;
  float sum = e;
  #pragma unroll
  for (int off = 1; off < 64; off <<= 1) sum += __shfl_xor(sum, off);
  if (tid < MM) S[(size_t)bn * SP + tid] = e / sum;
}

// ---------------- U partials: Upart[nt][b][m][d] = Sc_tile^T C2_tile ----------------
__global__ __launch_bounds__(256) void k_U(
    const float* __restrict__ Sc, const float* __restrict__ C2,
    float* __restrict__ Upart) {
  int b = blockIdx.x / 7, nt = blockIdx.x % 7;
  int n0 = nt * 64;
  int cnt = NN - n0; if (cnt > 64) cnt = 64;
  __shared__ float Scl[64][64];
  __shared__ float Cl[64][132];
  int tid = threadIdx.x;
  #pragma unroll
  for (int it = 0; it < 16; ++it) {
    int idx = it * 256 + tid;
    int n = idx >> 6, m = idx & 63;
    Scl[n][m] = (n < cnt && m < MM) ? Sc[((size_t)b * NN + n0 + n) * SP + m] : 0.f;
  }
  #pragma unroll
  for (int it = 0; it < 32; ++it) {
    int idx = it * 256 + tid;
    int n = idx >> 7, d = idx & 127;
    Cl[n][d] = (n < cnt) ? C2[((size_t)b * NN + n0 + n) * DD + d] : 0.f;
  }
  __syncthreads();
  int m0 = (tid >> 4) * 4, dt = tid & 15;
  int d0a = dt * 4, d0b = 64 + dt * 4;
  float acc[4][8] = {};
  for (int n = 0; n < 64; ++n) {
    float4 sv = *(const float4*)&Scl[n][m0];
    float4 ca = *(const float4*)&Cl[n][d0a];
    float4 cb = *(const float4*)&Cl[n][d0b];
    float sa[4] = {sv.x, sv.y, sv.z, sv.w};
    float cc[8] = {ca.x, ca.y, ca.z, ca.w, cb.x, cb.y, cb.z, cb.w};
    #pragma unroll
    for (int i = 0; i < 4; ++i)
      #pragma unroll
      for (int j = 0; j < 8; ++j) acc[i][j] += sa[i] * cc[j];
  }
  float* ubase = Upart + ((size_t)nt * BB + b) * MM * DD;
  #pragma unroll
  for (int i = 0; i < 4; ++i) {
    int m = m0 + i;
    if (m < MM) {
      float* ub = ubase + (size_t)m * DD;
      float4 w0 = make_float4(acc[i][0], acc[i][1], acc[i][2], acc[i][3]);
      float4 w1 = make_float4(acc[i][4], acc[i][5], acc[i][6], acc[i][7]);
      *(float4*)&ub[d0a] = w0;
      *(float4*)&ub[d0b] = w1;
    }
  }
}

// ---------------- reduce U partials ----------------
__global__ void k_Ured(const float* __restrict__ Upart, float* __restrict__ U) {
  int idx = blockIdx.x * 256 + threadIdx.x;
  if (idx >= BB * MM * DD) return;
  float s = 0.f;
  #pragma unroll
  for (int nt = 0; nt < 7; ++nt) s += Upart[(size_t)nt * BB * MM * DD + idx];
  U[idx] = s;
}

// ---------------- A,Bt = Sr @ {Q2,U}; fused final concat write (two-pass LDS) --------
__global__ __launch_bounds__(256) void k_ABtF(
    const float* __restrict__ Sr, const float* __restrict__ Q2,
    const float* __restrict__ U, const float* __restrict__ C2,
    float* __restrict__ out) {
  int b = blockIdx.x / 7, nt = blockIdx.x % 7;
  int n0 = nt * 64;
  __shared__ float Ml[MM][132];
  __shared__ float Srl[64][52];
  int tid = threadIdx.x;
  #pragma unroll
  for (int it = 0; it < 13; ++it) {
    int idx = it * 256 + tid;
    int n = idx / 52, m = idx % 52;
    Srl[n][m] = (n0 + n < NN) ? Sr[((size_t)b * NN + n0 + n) * SP + m] : 0.f;
  }
  #pragma unroll
  for (int it = 0; it < 25; ++it) {
    int idx = it * 256 + tid;
    int m = idx >> 7, d = idx & 127;
    Ml[m][d] = Q2[((size_t)b * MM + m) * DD + d];
  }
  __syncthreads();
  int nq = tid >> 4, dt = tid & 15;
  int d0a = dt * 4, d0b = 64 + dt * 4;
  float accA[4][8] = {}, accB[4][8] = {};
  for (int m = 0; m < MM; ++m) {
    float s[4];
    #pragma unroll
    for (int i = 0; i < 4; ++i) s[i] = Srl[nq * 4 + i][m];
    float4 qa = *(const float4*)&Ml[m][d0a];
    float4 qb = *(const float4*)&Ml[m][d0b];
    float qq[8] = {qa.x, qa.y, qa.z, qa.w, qb.x, qb.y, qb.z, qb.w};
    #pragma unroll
    for (int i = 0; i < 4; ++i)
      #pragma unroll
      for (int j = 0; j < 8; ++j) accA[i][j] += s[i] * qq[j];
  }
  __syncthreads();
  #pragma unroll
  for (int it = 0; it < 25; ++it) {
    int idx = it * 256 + tid;
    int m = idx >> 7, d = idx & 127;
    Ml[m][d] = U[((size_t)b * MM + m) * DD + d];
  }
  __syncthreads();
  for (int m = 0; m < MM; ++m) {
    float s[4];
    #pragma unroll
    for (int i = 0; i < 4; ++i) s[i] = Srl[nq * 4 + i][m];
    float4 ua = *(const float4*)&Ml[m][d0a];
    float4 ub = *(const float4*)&Ml[m][d0b];
    float uu[8] = {ua.x, ua.y, ua.z, ua.w, ub.x, ub.y, ub.z, ub.w};
    #pragma unroll
    for (int i = 0; i < 4; ++i)
      #pragma unroll
      for (int j = 0; j < 8; ++j) accB[i][j] += s[i] * uu[j];
  }
  #pragma unroll
  for (int i = 0; i < 4; ++i) {
    int n = n0 + nq * 4 + i;
    if (n < NN) {
      const float* c2r = C2 + ((size_t)b * NN + n) * DD;
      float4 ca = *(const float4*)&c2r[d0a];
      float4 cb = *(const float4*)&c2r[d0b];
      float cc[8] = {ca.x, ca.y, ca.z, ca.w, cb.x, cb.y, cb.z, cb.w};
      float* po = out + ((size_t)b * NN + n) * 512;
      float4 w0, w1;
      *(float4*)&po[d0a] = ca;
      *(float4*)&po[d0b] = cb;
      w0 = make_float4(accA[i][0], accA[i][1], accA[i][2], accA[i][3]);
      w1 = make_float4(accA[i][4], accA[i][5], accA[i][6], accA[i][7]);
      *(float4*)&po[128 + d0a] = w0;
      *(float4*)&po[128 + d0b] = w1;
      w0 = make_float4(cc[0]*accA[i][0], cc[1]*accA[i][1], cc[2]*accA[i][2], cc[3]*accA[i][3]);
      w1 = make_float4(cc[4]*accA[i][4], cc[5]*accA[i][5], cc[6]*accA[i][6], cc[7]*accA[i][7]);
      *(float4*)&po[256 + d0a] = w0;
      *(float4*)&po[256 + d0b] = w1;
      w0 = make_float4(cc[0]*accB[i][0], cc[1]*accB[i][1], cc[2]*accB[i][2], cc[3]*accB[i][3]);
      w1 = make_float4(cc[4]*accB[i][4], cc[5]*accB[i][5], cc[6]*accB[i][6], cc[7]*accB[i][7]);
      *(float4*)&po[384 + d0a] = w0;
      *(float4*)&po[384 + d0b] = w1;
    }
  }
}

extern "C" void kernel_launch(void* const* d_in, const int* in_sizes, int n_in,
                              void* d_out, int out_size, void* d_ws, size_t ws_size,
                              hipStream_t stream) {
  (void)in_sizes; (void)n_in; (void)out_size; (void)ws_size;
  const float* ctx   = (const float*)d_in[0];
  const float* que   = (const float*)d_in[1];
  const float* cmask = (const float*)d_in[2];
  const float* qmask = (const float*)d_in[3];
  const float* ln_g  = (const float*)d_in[4];
  const float* ln_b  = (const float*)d_in[5];
  const float* dw_w  = (const float*)d_in[6];
  const float* dw_b  = (const float*)d_in[7];
  const float* pw_w  = (const float*)d_in[8];
  const float* pw_b  = (const float*)d_in[9];
  const float* Wq    = (const float*)d_in[10];
  const float* bq    = (const float*)d_in[11];
  const float* Wk    = (const float*)d_in[12];
  const float* bk    = (const float*)d_in[13];
  const float* Wv    = (const float*)d_in[14];
  const float* bv    = (const float*)d_in[15];
  const float* Wo    = (const float*)d_in[16];
  const float* bo    = (const float*)d_in[17];
  const float* Wfc   = (const float*)d_in[18];
  const float* bfc   = (const float*)d_in[19];
  const float* cq_wc = (const float*)d_in[20];
  const float* cq_wq = (const float*)d_in[21];
  const float* cq_wm = (const float*)d_in[22];
  const float* cq_b  = (const float*)d_in[23];
  float* out = (float*)d_out;
  float* ws = (float*)d_ws;

  float* Cb   = ws;
  float* Qb   = Cb + SZ_C;
  float* t1C  = Qb + SZ_Q;
  float* t1Q  = t1C + SZ_C;
  float* t2C  = t1Q + SZ_Q;
  float* t2Q  = t2C + SZ_C;
  float* t3C  = t2Q + SZ_Q;
  float* t3Q  = t3C + SZ_C;
  float* t4C  = t3Q + SZ_Q;
  float* t4Q  = t4C + SZ_C;
  float* muB  = t4Q + SZ_Q;
  float* invB = muB + SSTAT;
  float* Wcan = invB + SSTAT;

  int totAll = SZ_C + SZ_Q;
  int nbAll = (totAll + 255) / 256;

  k_transposeW<<<(9 * 16384 + 255) / 256, 256, 0, stream>>>(pw_w, Wo, Wfc, Wq, Wk, Wv, Wcan);
  k_pe<<<nbAll, 256, 0, stream>>>(ctx, que, Cb, Qb);

  // conv layers (ping-pong Cb <-> t1C)
  const float* srcC = Cb; const float* srcQ = Qb;
  float* dstC = t1C; float* dstQ = t1Q;
  for (int i = 0; i < NC; ++i) {
    k_lnstats<<<512, 256, 0, stream>>>(srcC, srcQ, muB, invB);
    k_gemmconv<<<1024, 256, 0, stream>>>(srcC, srcQ, dstC, dstQ,
                                         dw_w + (size_t)i * DD * KW, dw_b + (size_t)i * DD,
                                         Wcan + (size_t)i * 16384, pw_b + (size_t)i * DD,
                                         muB, invB, ln_g, ln_b);
    float* tC = (float*)srcC; float* tQ = (float*)srcQ;
    srcC = dstC; srcQ = dstQ; dstC = tC; dstQ = tQ;
  }
  // after 4 layers (NC even): Cb/Qb hold encoder state
  // self-attention
  k_lnstats<<<512, 256, 0, stream>>>(Cb, Qb, muB, invB);
  k_gemmA<<<64 * 48, 256, 0, stream>>>(Cb, Qb, t1C, t1Q, t2C, t2Q, t3C, t3Q,
                                       Wcan + 6 * 16384, bq, bk, bv, muB, invB, ln_g, ln_b);
  k_attn4<<<7680, 256, 0, stream>>>(t1C, t2C, t3C, t1Q, t2Q, t3Q, cmask, qmask, t4C, t4Q);
  k_gemmB<0><<<1024, 256, 0, stream>>>(t4C, t4Q, Cb, Qb, Cb, Qb,
                                       Wcan + 4 * 16384, bo, muB, invB, ln_g, ln_b);
  // FFN
  k_lnstats<<<512, 256, 0, stream>>>(Cb, Qb, muB, invB);
  k_gemmB<1><<<1024, 256, 0, stream>>>(Cb, Qb, Cb, Qb, t1C, t1Q,
                                       Wcan + 5 * 16384, bfc, muB, invB, ln_g, ln_b);

  // ---- context-query attention ----
  float* C2    = t2C;
  float* Q2    = t2Q;
  float* S     = t3C;   // pitch SP
  float* Scb   = t4C;   // pitch SP
  float* Uu    = t3Q;
  float* cd    = t4Q;
  float* qd    = t4Q + BB * NN;
  float* Upart = t1C;   // 7*64*50*128 = 2.87M floats, fits in t1C (free after dotD)

  int totC = BB * NN * DD;
  int totQ = BB * MM * DD;
  k_transpose<<<(totC + 255) / 256, 256, 0, stream>>>(t1C, C2, NN, totC);
  k_transpose<<<(totQ + 255) / 256, 256, 0, stream>>>(t1Q, Q2, MM, totQ);
  k_dotD<<<(BB * NN + 255) / 256, 256, 0, stream>>>(t1C, cq_wc, cd, NN, BB * NN);
  k_dotD<<<(BB * MM + 255) / 256, 256, 0, stream>>>(t1Q, cq_wq, qd, MM, BB * MM);
  k_S<<<64 * 7, 256, 0, stream>>>(C2, Q2, cd, qd, cq_wm, cq_b, S);
  k_smax_col<<<BB * MM, 64, 0, stream>>>(S, cmask, Scb);
  k_smax_row<<<BB * NN, 64, 0, stream>>>(S, qmask); // S now holds S_r
  k_U<<<64 * 7, 256, 0, stream>>>(Scb, C2, Upart);
  k_Ured<<<(BB * MM * DD + 255) / 256, 256, 0, stream>>>(Upart, Uu);
  k_ABtF<<<64 * 7, 256, 0, stream>>>(S, Q2, Uu, C2, out);
}

// Round 6
// 1140.524 us; speedup vs baseline: 1.3858x; 1.3858x over previous
//
#include <hip/hip_runtime.h>
#include <math.h>

#define BB 64
#define DD 128
#define NN 400
#define MM 50
#define HH 8
#define KDIM 16
#define NC 4
#define KW 7
#define SP 52   // pitched S row

#define SZ_C (BB * DD * NN)   // 3,276,800
#define SZ_Q (BB * DD * MM)   //   409,600
#define SSTAT (BB * NN + BB * MM)

// ---------------- canonical weight transpose: Wcan[m][d][e] ----------------
__global__ void k_transposeW(const float* __restrict__ pw_w, const float* __restrict__ Wo,
                             const float* __restrict__ Wfc, const float* __restrict__ Wq,
                             const float* __restrict__ Wk, const float* __restrict__ Wv,
                             float* __restrict__ Wcan) {
  int idx = blockIdx.x * 256 + threadIdx.x;
  if (idx >= 9 * 16384) return;
  int m = idx >> 14;
  int r = idx & 16383;
  int d = r >> 7, e = r & 127;
  float v;
  if (m < 4) v = pw_w[m * 16384 + e * 128 + d];
  else if (m == 4) v = Wo[d * 128 + e];
  else if (m == 5) v = Wfc[e * 128 + d];
  else {
    const float* W = (m == 6) ? Wq : (m == 7) ? Wk : Wv;
    v = W[((e >> 4) * 128 + d) * 16 + (e & 15)];
  }
  Wcan[idx] = v;
}

// ---------------- position encoding add ----------------
__global__ void k_pe(const float* __restrict__ xC, const float* __restrict__ xQ,
                     float* __restrict__ yC, float* __restrict__ yQ) {
  int idx = blockIdx.x * 256 + threadIdx.x;
  const float* x; float* y; int L, id2;
  if (idx < SZ_C) { x = xC; y = yC; L = NN; id2 = idx; }
  else if (idx < SZ_C + SZ_Q) { x = xQ; y = yQ; L = MM; id2 = idx - SZ_C; }
  else return;
  int l = id2 % L;
  int d = (id2 / L) % DD;
  int de = d & ~1;
  float freq = __expf((float)de * (-9.210340371976184f / 128.0f));
  float phase = (d & 1) ? 1.5707963267948966f : 0.0f;
  y[id2] = x[id2] + sinf((float)l * freq + phase);
}

// ---------------- LN stats ----------------
__global__ void k_lnstats(const float* __restrict__ xC, const float* __restrict__ xQ,
                          float* __restrict__ mu, float* __restrict__ inv) {
  int blk = blockIdx.x;
  const float* x; int L, lt, b, soff;
  if (blk < 448) { b = blk / 7; lt = blk % 7; x = xC; L = NN; soff = 0; }
  else { b = blk - 448; lt = 0; x = xQ; L = MM; soff = BB * NN; }
  int ll = threadIdx.x & 63;
  int dq = threadIdx.x >> 6;
  int l = lt * 64 + ll;
  __shared__ float s_sum[4][64], s_sq[4][64];
  float sum = 0.f, sq = 0.f;
  const float* px = x + (size_t)b * DD * L + l;
  if (l < L) {
    for (int d = dq * 32; d < dq * 32 + 32; ++d) {
      float v = px[(size_t)d * L];
      sum += v; sq += v * v;
    }
  }
  s_sum[dq][ll] = sum; s_sq[dq][ll] = sq;
  __syncthreads();
  if (dq == 0 && l < L) {
    float ts = s_sum[0][ll] + s_sum[1][ll] + s_sum[2][ll] + s_sum[3][ll];
    float tq = s_sq[0][ll] + s_sq[1][ll] + s_sq[2][ll] + s_sq[3][ll];
    float m = ts * (1.0f / 128.0f);
    float var = (tq - 128.0f * m * m) * (1.0f / 127.0f);
    float sd = sqrtf(fmaxf(var, 0.f));
    mu[soff + b * L + l] = m;
    inv[soff + b * L + l] = 1.0f / (sd + 1e-6f);
  }
}

__device__ inline void mma16(float4 wv, float4 xv, float acc[4][4]) {
  float wa[4] = {wv.x, wv.y, wv.z, wv.w};
  float xa[4] = {xv.x, xv.y, xv.z, xv.w};
  #pragma unroll
  for (int i = 0; i < 4; ++i)
    #pragma unroll
    for (int j = 0; j < 4; ++j) acc[i][j] += wa[i] * xa[j];
}

// ---------------- fused LN + depthwise conv + pointwise GEMM + relu + residual ----------
__global__ __launch_bounds__(256) void k_gemmconv(
    const float* __restrict__ xC, const float* __restrict__ xQ,
    float* __restrict__ yC, float* __restrict__ yQ,
    const float* __restrict__ w7, const float* __restrict__ dwb,
    const float* __restrict__ Wc, const float* __restrict__ pwb,
    const float* __restrict__ mu, const float* __restrict__ inv,
    const float* __restrict__ g, const float* __restrict__ beta) {
  int b = blockIdx.x >> 4, t = blockIdx.x & 15;
  const float* x; float* y; int L, l0, et, soff;
  if (t < 14) { x = xC; y = yC; L = NN; l0 = (t >> 1) * 64; et = t & 1; soff = 0; }
  else { x = xQ; y = yQ; L = MM; l0 = 0; et = t - 14; soff = BB * NN; }
  int e0b = et * 64;
  __shared__ float Xr[32][72];
  __shared__ float Xc[32][68];
  __shared__ float Wl[32][64];
  int tid = threadIdx.x;
  float acc[4][4] = {};
  const float* xb = x + (size_t)b * DD * L;
  const float* pmu = mu + soff + b * L;
  const float* pin = inv + soff + b * L;
  for (int kc = 0; kc < 4; ++kc) {
    int d0 = kc * 32;
    #pragma unroll
    for (int it = 0; it < 9; ++it) {
      int idx = it * 256 + tid;
      int d = idx / 72, lx = idx % 72;
      float v = 0.f;
      int gl = l0 - 3 + lx;
      if (lx < 70 && gl >= 0 && gl < L) {
        v = xb[(size_t)(d0 + d) * L + gl];
        v = g[d0 + d] * (v - pmu[gl]) * pin[gl] + beta[d0 + d];
      }
      Xr[d][lx] = v;
    }
    #pragma unroll
    for (int it = 0; it < 8; ++it) {
      int idx = it * 256 + tid;
      int k = idx >> 6, e = idx & 63;
      Wl[k][e] = Wc[(size_t)(d0 + k) * DD + e0b + e];
    }
    __syncthreads();
    #pragma unroll
    for (int it = 0; it < 8; ++it) {
      int idx = it * 256 + tid;
      int d = idx >> 6, l = idx & 63;
      const float* wr = w7 + (size_t)(d0 + d) * KW;
      float a = dwb[d0 + d];
      #pragma unroll
      for (int k = 0; k < 7; ++k) a += wr[k] * Xr[d][l + k];
      Xc[d][l] = a;
    }
    __syncthreads();
    int te = (tid >> 4) * 4, tl = (tid & 15) * 4;
    for (int k = 0; k < 32; ++k) {
      float4 wv = *(const float4*)&Wl[k][te];
      float4 xv = *(const float4*)&Xc[k][tl];
      mma16(wv, xv, acc);
    }
    __syncthreads();
  }
  int te = e0b + (tid >> 4) * 4, tl = l0 + (tid & 15) * 4;
  #pragma unroll
  for (int i = 0; i < 4; ++i) {
    int e = te + i;
    float bi = pwb[e];
    float* po = y + ((size_t)b * DD + e) * L;
    const float* pr = x + ((size_t)b * DD + e) * L;
    if (L == NN && tl + 3 < NN) {
      float4 rv = *(const float4*)&pr[tl];
      float4 ov;
      ov.x = fmaxf(acc[i][0] + bi, 0.f) + rv.x;
      ov.y = fmaxf(acc[i][1] + bi, 0.f) + rv.y;
      ov.z = fmaxf(acc[i][2] + bi, 0.f) + rv.z;
      ov.w = fmaxf(acc[i][3] + bi, 0.f) + rv.w;
      *(float4*)&po[tl] = ov;
    } else {
      #pragma unroll
      for (int j = 0; j < 4; ++j) {
        int l = tl + j;
        if (l < L) po[l] = fmaxf(acc[i][j] + bi, 0.f) + pr[l];
      }
    }
  }
}

// ---------------- plain 128x128 GEMM (Wo / FC), +bias +residual ----------------
template <int LNF>
__global__ __launch_bounds__(256) void k_gemmB(
    const float* __restrict__ xC, const float* __restrict__ xQ,
    const float* __restrict__ resC, const float* __restrict__ resQ,
    float* __restrict__ yC, float* __restrict__ yQ,
    const float* __restrict__ Wc, const float* __restrict__ bias,
    const float* __restrict__ mu, const float* __restrict__ inv,
    const float* __restrict__ g, const float* __restrict__ beta) {
  int b = blockIdx.x >> 4, t = blockIdx.x & 15;
  const float *x, *res; float* y; int L, l0, et, soff;
  if (t < 14) { x = xC; res = resC; y = yC; L = NN; l0 = (t >> 1) * 64; et = t & 1; soff = 0; }
  else { x = xQ; res = resQ; y = yQ; L = MM; l0 = 0; et = t - 14; soff = BB * NN; }
  int e0b = et * 64;
  __shared__ float Xl[32][68];
  __shared__ float Wl[32][64];
  int tid = threadIdx.x;
  float acc[4][4] = {};
  const float* xb = x + (size_t)b * DD * L;
  const float* pmu = mu + soff + b * L;
  const float* pin = inv + soff + b * L;
  for (int kc = 0; kc < 4; ++kc) {
    int d0 = kc * 32;
    #pragma unroll
    for (int it = 0; it < 8; ++it) {
      int idx = it * 256 + tid;
      int k = idx >> 6, l = idx & 63;
      float v = 0.f;
      int gl = l0 + l;
      if (gl < L) {
        v = xb[(size_t)(d0 + k) * L + gl];
        if (LNF) v = g[d0 + k] * (v - pmu[gl]) * pin[gl] + beta[d0 + k];
      }
      Xl[k][l] = v;
    }
    #pragma unroll
    for (int it = 0; it < 8; ++it) {
      int idx = it * 256 + tid;
      int k = idx >> 6, e = idx & 63;
      Wl[k][e] = Wc[(size_t)(d0 + k) * DD + e0b + e];
    }
    __syncthreads();
    int te = (tid >> 4) * 4, tl = (tid & 15) * 4;
    for (int k = 0; k < 32; ++k) {
      float4 wv = *(const float4*)&Wl[k][te];
      float4 xv = *(const float4*)&Xl[k][tl];
      mma16(wv, xv, acc);
    }
    __syncthreads();
  }
  int te = e0b + (tid >> 4) * 4, tl = l0 + (tid & 15) * 4;
  #pragma unroll
  for (int i = 0; i < 4; ++i) {
    int e = te + i;
    float bi = bias[e];
    float* po = y + ((size_t)b * DD + e) * L;
    const float* pr = res + ((size_t)b * DD + e) * L;
    if (L == NN && tl + 3 < NN) {
      float4 rv = *(const float4*)&pr[tl];
      float4 ov;
      ov.x = acc[i][0] + bi + rv.x;
      ov.y = acc[i][1] + bi + rv.y;
      ov.z = acc[i][2] + bi + rv.z;
      ov.w = acc[i][3] + bi + rv.w;
      *(float4*)&po[tl] = ov;
    } else {
      #pragma unroll
      for (int j = 0; j < 4; ++j) {
        int l = tl + j;
        if (l < L) po[l] = acc[i][j] + bi + pr[l];
      }
    }
  }
}

// ---------------- QKV GEMM: one launch; Q -> plane layout, K/V -> [bh][l][16] ----------
__global__ __launch_bounds__(256) void k_gemmA(
    const float* __restrict__ xC, const float* __restrict__ xQ,
    float* __restrict__ qC, float* __restrict__ qQ,
    float* __restrict__ ktC, float* __restrict__ ktQ,
    float* __restrict__ vtC, float* __restrict__ vtQ,
    const float* __restrict__ Wcan6,
    const float* __restrict__ bq, const float* __restrict__ bk, const float* __restrict__ bv,
    const float* __restrict__ mu, const float* __restrict__ inv,
    const float* __restrict__ g, const float* __restrict__ beta) {
  int b = blockIdx.x / 48, t = blockIdx.x % 48;
  const float* x; float *qp, *ktp, *vtp; int L, l0, e6, soff;
  if (t < 42) { x = xC; qp = qC; ktp = ktC; vtp = vtC; L = NN; l0 = (t / 6) * 64; e6 = t % 6; soff = 0; }
  else { x = xQ; qp = qQ; ktp = ktQ; vtp = vtQ; L = MM; l0 = 0; e6 = t - 42; soff = BB * NN; }
  int w = e6 >> 1, et = e6 & 1, e0b = et * 64;
  const float* Wc = Wcan6 + (size_t)w * 16384;
  const float* bias = (w == 0) ? bq : (w == 1) ? bk : bv;
  __shared__ float Xl[32][68];
  __shared__ float Wl[32][64];
  int tid = threadIdx.x;
  float acc[4][4] = {};
  const float* xb = x + (size_t)b * DD * L;
  const float* pmu = mu + soff + b * L;
  const float* pin = inv + soff + b * L;
  for (int kc = 0; kc < 4; ++kc) {
    int d0 = kc * 32;
    #pragma unroll
    for (int it = 0; it < 8; ++it) {
      int idx = it * 256 + tid;
      int k = idx >> 6, l = idx & 63;
      float v = 0.f;
      int gl = l0 + l;
      if (gl < L) {
        v = xb[(size_t)(d0 + k) * L + gl];
        v = g[d0 + k] * (v - pmu[gl]) * pin[gl] + beta[d0 + k];
      }
      Xl[k][l] = v;
    }
    #pragma unroll
    for (int it = 0; it < 8; ++it) {
      int idx = it * 256 + tid;
      int k = idx >> 6, e = idx & 63;
      Wl[k][e] = Wc[(size_t)(d0 + k) * DD + e0b + e];
    }
    __syncthreads();
    int te = (tid >> 4) * 4, tl = (tid & 15) * 4;
    for (int k = 0; k < 32; ++k) {
      float4 wv = *(const float4*)&Wl[k][te];
      float4 xv = *(const float4*)&Xl[k][tl];
      mma16(wv, xv, acc);
    }
    __syncthreads();
  }
  int te = e0b + (tid >> 4) * 4, tl = l0 + (tid & 15) * 4;
  if (w == 0) {
    #pragma unroll
    for (int i = 0; i < 4; ++i) {
      int e = te + i;
      float bi = bias[e];
      float* po = qp + ((size_t)b * DD + e) * L;
      #pragma unroll
      for (int j = 0; j < 4; ++j) {
        int l = tl + j;
        if (l < L) po[l] = acc[i][j] + bi;
      }
    }
  } else {
    float* dst = (w == 1) ? ktp : vtp;
    int h = te >> 4, t0 = te & 15;
    float b0 = bias[te], b1 = bias[te + 1], b2 = bias[te + 2], b3 = bias[te + 3];
    size_t bhL = (size_t)(b * 8 + h) * L;
    #pragma unroll
    for (int j = 0; j < 4; ++j) {
      int l = tl + j;
      if (l < L) {
        float4 val;
        val.x = acc[0][j] + b0;
        val.y = acc[1][j] + b1;
        val.z = acc[2][j] + b2;
        val.w = acc[3][j] + b3;
        *(float4*)&dst[(bhL + l) * 16 + t0] = val;
      }
    }
  }
}

// ---------------- register-tiled flash attention, conflict-free LDS ----------------
// 256 thr = 16 ti x 16 tj; thread owns i = i0+ti*2+{0,1}, keys j = jt*64 + tj + 16*jj.
// K/V rows at pitch 20 words (80B): base bank = 20*tj mod 32 -> worst 2-way (free),
// 4-way same-address broadcast across ti (free). Mask penalty in pad word [16].
__global__ __launch_bounds__(256) void k_attn5(
    const float* __restrict__ qC, const float* __restrict__ ktC, const float* __restrict__ vtC,
    const float* __restrict__ qQ, const float* __restrict__ ktQ, const float* __restrict__ vtQ,
    const float* __restrict__ cmask, const float* __restrict__ qmask,
    float* __restrict__ oC, float* __restrict__ oQ) {
  int blk = blockIdx.x;
  const float *qp, *kt, *vt, *mk; float* op; int L, b, h, i0;
  if (blk < 6656) {
    int bh = blk / 13, it = blk % 13;
    b = bh >> 3; h = bh & 7; i0 = it * 32;
    qp = qC; kt = ktC; vt = vtC; mk = cmask; op = oC; L = NN;
  } else {
    int r = blk - 6656; int bh = r >> 1; int it = r & 1;
    b = bh >> 3; h = bh & 7; i0 = it * 32;
    qp = qQ; kt = ktQ; vt = vtQ; mk = qmask; op = oQ; L = MM;
  }
  __shared__ float Sh[16000];   // Kl 8000 | Vl 8000 (pitch 20; pen in word 16) = 64000B
  float* Kl = Sh;
  float* Vl = Sh + 8000;
  int tid = threadIdx.x;
  size_t kvbase = (size_t)(b * 8 + h) * L * 16;
  const float4* kg = (const float4*)(kt + kvbase);
  const float4* vg = (const float4*)(vt + kvbase);
  for (int x = tid; x < L * 4; x += 256) {
    int j = x >> 2, q = x & 3;
    *(float4*)&Kl[j * 20 + q * 4] = kg[x];
    *(float4*)&Vl[j * 20 + q * 4] = vg[x];
  }
  for (int j = tid; j < L; j += 256)
    Kl[j * 20 + 16] = -1e30f * (1.0f - mk[b * L + j]);
  __syncthreads();

  int ti = tid >> 4, tj = tid & 15;
  int iA = i0 + ti * 2, iB = iA + 1;
  bool aA = iA < L, aB = iB < L;
  size_t qbase = ((size_t)b * DD + h * 16) * L;
  float q0[16], q1[16];
  #pragma unroll
  for (int t = 0; t < 16; ++t) {
    q0[t] = aA ? qp[qbase + (size_t)t * L + iA] : 0.f;
    q1[t] = aB ? qp[qbase + (size_t)t * L + iB] : 0.f;
  }
  float m0r = -1e30f, m1r = -1e30f, l0r = 0.f, l1r = 0.f;
  float O0[16] = {}, O1[16] = {};
  int njt = (L + 63) >> 6;
  for (int jt = 0; jt < njt; ++jt) {
    float s0[4], s1[4];
    #pragma unroll
    for (int jj = 0; jj < 4; ++jj) {
      int j = jt * 64 + tj + 16 * jj;
      int jc = j < L ? j : L - 1;
      const float4* kr = (const float4*)&Kl[jc * 20];
      float4 k0 = kr[0], k1 = kr[1], k2 = kr[2], k3 = kr[3];
      float d0 = q0[0]*k0.x + q0[1]*k0.y + q0[2]*k0.z + q0[3]*k0.w
               + q0[4]*k1.x + q0[5]*k1.y + q0[6]*k1.z + q0[7]*k1.w
               + q0[8]*k2.x + q0[9]*k2.y + q0[10]*k2.z + q0[11]*k2.w
               + q0[12]*k3.x + q0[13]*k3.y + q0[14]*k3.z + q0[15]*k3.w;
      float d1 = q1[0]*k0.x + q1[1]*k0.y + q1[2]*k0.z + q1[3]*k0.w
               + q1[4]*k1.x + q1[5]*k1.y + q1[6]*k1.z + q1[7]*k1.w
               + q1[8]*k2.x + q1[9]*k2.y + q1[10]*k2.z + q1[11]*k2.w
               + q1[12]*k3.x + q1[13]*k3.y + q1[14]*k3.z + q1[15]*k3.w;
      float pen = (j < L) ? Kl[j * 20 + 16] : -1e30f;
      s0[jj] = d0 * 0.25f + pen;
      s1[jj] = d1 * 0.25f + pen;
    }
    float t0 = fmaxf(fmaxf(s0[0], s0[1]), fmaxf(s0[2], s0[3]));
    float t1 = fmaxf(fmaxf(s1[0], s1[1]), fmaxf(s1[2], s1[3]));
    #pragma unroll
    for (int off = 1; off < 16; off <<= 1) {
      t0 = fmaxf(t0, __shfl_xor(t0, off));
      t1 = fmaxf(t1, __shfl_xor(t1, off));
    }
    float nm0 = fmaxf(m0r, t0), nm1 = fmaxf(m1r, t1);
    float sc0 = __expf(m0r - nm0), sc1 = __expf(m1r - nm1);
    l0r *= sc0; l1r *= sc1;
    #pragma unroll
    for (int t = 0; t < 16; ++t) { O0[t] *= sc0; O1[t] *= sc1; }
    m0r = nm0; m1r = nm1;
    #pragma unroll
    for (int jj = 0; jj < 4; ++jj) {
      int j = jt * 64 + tj + 16 * jj;
      int jc = j < L ? j : L - 1;
      float p0 = __expf(s0[jj] - m0r);
      float p1 = __expf(s1[jj] - m1r);
      l0r += p0; l1r += p1;
      const float4* vr = (const float4*)&Vl[jc * 20];
      float4 v0 = vr[0], v1 = vr[1], v2 = vr[2], v3 = vr[3];
      O0[0] += p0*v0.x;  O0[1] += p0*v0.y;  O0[2] += p0*v0.z;  O0[3] += p0*v0.w;
      O0[4] += p0*v1.x;  O0[5] += p0*v1.y;  O0[6] += p0*v1.z;  O0[7] += p0*v1.w;
      O0[8] += p0*v2.x;  O0[9] += p0*v2.y;  O0[10] += p0*v2.z; O0[11] += p0*v2.w;
      O0[12] += p0*v3.x; O0[13] += p0*v3.y; O0[14] += p0*v3.z; O0[15] += p0*v3.w;
      O1[0] += p1*v0.x;  O1[1] += p1*v0.y;  O1[2] += p1*v0.z;  O1[3] += p1*v0.w;
      O1[4] += p1*v1.x;  O1[5] += p1*v1.y;  O1[6] += p1*v1.z;  O1[7] += p1*v1.w;
      O1[8] += p1*v2.x;  O1[9] += p1*v2.y;  O1[10] += p1*v2.z; O1[11] += p1*v2.w;
      O1[12] += p1*v3.x; O1[13] += p1*v3.y; O1[14] += p1*v3.z; O1[15] += p1*v3.w;
    }
  }
  // ---- cross-tj reduction via LDS (pad-17 stride), then write ----
  __syncthreads();  // everyone done with Kl/Vl
  #pragma unroll
  for (int t = 0; t < 16; ++t) {
    Sh[((0 * 16 + ti) * 16 + t) * 17 + tj] = O0[t];
    Sh[((1 * 16 + ti) * 16 + t) * 17 + tj] = O1[t];
  }
  Sh[8704 + (ti * 2 + 0) * 17 + tj] = l0r;
  Sh[8704 + (ti * 2 + 1) * 17 + tj] = l1r;
  __syncthreads();
  #pragma unroll
  for (int r = 0; r < 2; ++r) {
    int o = tid * 2 + r;
    int t = o & 15, ti2 = (o >> 4) & 15, ii = o >> 8;
    int i = i0 + ti2 * 2 + ii;
    if (i < L) {
      float s = 0.f, ls = 0.f;
      #pragma unroll
      for (int k = 0; k < 16; ++k) {
        s += Sh[o * 17 + k];
        ls += Sh[8704 + (ti2 * 2 + ii) * 17 + k];
      }
      op[qbase + (size_t)t * L + i] = s / ls;
    }
  }
}

// ---------------- [B,D,L] -> [B,L,D] transpose ----------------
__global__ void k_transpose(const float* __restrict__ X, float* __restrict__ Y,
                            int L, int total) {
  int idx = blockIdx.x * 256 + threadIdx.x;
  if (idx >= total) return;
  int d = idx % DD;
  int l = (idx / DD) % L;
  int b = idx / (DD * L);
  Y[idx] = X[((size_t)b * DD + d) * L + l];
}

// ---------------- dot over D: out[b,l] = sum_d X[b,d,l]*w[d] ----------------
__global__ void k_dotD(const float* __restrict__ X, const float* __restrict__ w,
                       float* __restrict__ out, int L, int total) {
  int idx = blockIdx.x * 256 + threadIdx.x;
  if (idx >= total) return;
  int l = idx % L;
  int b = idx / L;
  const float* px = X + (size_t)b * DD * L + l;
  float acc = 0.f;
  for (int d = 0; d < DD; ++d) acc += px[(size_t)d * L] * w[d];
  out[idx] = acc;
}

// ---------------- S trilinear, tiled GEMM; S pitch SP ----------------
__global__ __launch_bounds__(256) void k_S(
    const float* __restrict__ C2, const float* __restrict__ Q2,
    const float* __restrict__ cd, const float* __restrict__ qd,
    const float* __restrict__ wm, const float* __restrict__ cqb,
    float* __restrict__ S) {
  int b = blockIdx.x / 7, nt = blockIdx.x % 7;
  int n0 = nt * 64;
  __shared__ float Qw[DD][64];
  __shared__ float Cl[32][68];
  int tid = threadIdx.x;
  #pragma unroll
  for (int it = 0; it < 25; ++it) {
    int idx = it * 256 + tid;
    int m = idx >> 7, d = idx & 127;
    Qw[d][m] = Q2[((size_t)b * MM + m) * DD + d] * wm[d];
  }
  for (int it = 0; it < 7; ++it) {
    int idx = it * 256 + tid;
    if (idx < 128 * 14) Qw[idx / 14][50 + idx % 14] = 0.f;
  }
  float acc[4][4] = {};
  const float* c2b = C2 + (size_t)b * NN * DD;
  for (int kc = 0; kc < 4; ++kc) {
    int d0 = kc * 32;
    #pragma unroll
    for (int it = 0; it < 8; ++it) {
      int idx = it * 256 + tid;
      int n = idx >> 5, k = idx & 31;
      int gn = n0 + n;
      Cl[k][n] = (gn < NN) ? c2b[(size_t)gn * DD + d0 + k] : 0.f;
    }
    __syncthreads();
    int tm = (tid >> 4) * 4, tn = (tid & 15) * 4;
    for (int k = 0; k < 32; ++k) {
      float4 qv = *(const float4*)&Qw[d0 + k][tm];
      float4 cv = *(const float4*)&Cl[k][tn];
      mma16(qv, cv, acc);
    }
    __syncthreads();
  }
  int tm = (tid >> 4) * 4, tn0 = n0 + (tid & 15) * 4;
  if (tm < MM) {
    float qv[4];
    #pragma unroll
    for (int i = 0; i < 4; ++i) qv[i] = (tm + i < MM) ? qd[b * MM + tm + i] : 0.f;
    float bias0 = cqb[0];
    #pragma unroll
    for (int j = 0; j < 4; ++j) {
      int n = tn0 + j;
      if (n < NN) {
        float cdv = cd[b * NN + n] + bias0;
        float4 val;
        val.x = acc[0][j] + qv[0] + cdv;
        val.y = acc[1][j] + qv[1] + cdv;
        val.z = acc[2][j] + qv[2] + cdv;
        val.w = acc[3][j] + qv[3] + cdv;
        *(float4*)&S[((size_t)b * NN + n) * SP + tm] = val;
      }
    }
  }
}

// ---------------- softmax over n (col) -> Sc; pitch SP ----------------
__global__ void k_smax_col(const float* __restrict__ S, const float* __restrict__ cmask,
                           float* __restrict__ Sc) {
  int b = blockIdx.x / MM;
  int mcol = blockIdx.x % MM;
  int tid = threadIdx.x;
  float vals[7];
  float mx = -1e30f;
  #pragma unroll
  for (int c = 0; c < 7; ++c) {
    int n = tid + c * 64;
    float s = -1e30f;
    if (n < NN)
      s = S[((size_t)b * NN + n) * SP + mcol] - 1e30f * (1.0f - cmask[b * NN + n]);
    vals[c] = s;
    mx = fmaxf(mx, s);
  }
  #pragma unroll
  for (int off = 1; off < 64; off <<= 1) mx = fmaxf(mx, __shfl_xor(mx, off));
  float sum = 0.f;
  #pragma unroll
  for (int c = 0; c < 7; ++c) { vals[c] = __expf(vals[c] - mx); sum += vals[c]; }
  #pragma unroll
  for (int off = 1; off < 64; off <<= 1) sum += __shfl_xor(sum, off);
  float inv = 1.0f / sum;
  #pragma unroll
  for (int c = 0; c < 7; ++c) {
    int n = tid + c * 64;
    if (n < NN) Sc[((size_t)b * NN + n) * SP + mcol] = vals[c] * inv;
  }
}

// ---------------- softmax over m (row), in-place; pitch SP ----------------
__global__ void k_smax_row(float* __restrict__ S, const float* __restrict__ qmask) {
  int bn = blockIdx.x;
  int b = bn / NN;
  int tid = threadIdx.x;
  float s = -1e30f;
  if (tid < MM)
    s = S[(size_t)bn * SP + tid] - 1e30f * (1.0f - qmask[b * MM + tid]);
  float mx = s;
  #pragma unroll
  for (int off = 1; off < 64; off <<= 1) mx = fmaxf(mx, __shfl_xor(mx, off));
  float e = (tid < MM) ? __expf(s - mx) : 0.f;
  float sum = e;
  #pragma unroll
  for (int off = 1; off < 64; off <<= 1) sum += __shfl_xor(sum, off);
  if (tid < MM) S[(size_t)bn * SP + tid] = e / sum;
}

// ---------------- U partials: Upart[nt][b][m][d] = Sc_tile^T C2_tile ----------------
__global__ __launch_bounds__(256) void k_U(
    const float* __restrict__ Sc, const float* __restrict__ C2,
    float* __restrict__ Upart) {
  int b = blockIdx.x / 7, nt = blockIdx.x % 7;
  int n0 = nt * 64;
  int cnt = NN - n0; if (cnt > 64) cnt = 64;
  __shared__ float Scl[64][64];
  __shared__ float Cl[64][132];
  int tid = threadIdx.x;
  #pragma unroll
  for (int it = 0; it < 16; ++it) {
    int idx = it * 256 + tid;
    int n = idx >> 6, m = idx & 63;
    Scl[n][m] = (n < cnt && m < MM) ? Sc[((size_t)b * NN + n0 + n) * SP + m] : 0.f;
  }
  #pragma unroll
  for (int it = 0; it < 32; ++it) {
    int idx = it * 256 + tid;
    int n = idx >> 7, d = idx & 127;
    Cl[n][d] = (n < cnt) ? C2[((size_t)b * NN + n0 + n) * DD + d] : 0.f;
  }
  __syncthreads();
  int m0 = (tid >> 4) * 4, dt = tid & 15;
  int d0a = dt * 4, d0b = 64 + dt * 4;
  float acc[4][8] = {};
  for (int n = 0; n < 64; ++n) {
    float4 sv = *(const float4*)&Scl[n][m0];
    float4 ca = *(const float4*)&Cl[n][d0a];
    float4 cb = *(const float4*)&Cl[n][d0b];
    float sa[4] = {sv.x, sv.y, sv.z, sv.w};
    float cc[8] = {ca.x, ca.y, ca.z, ca.w, cb.x, cb.y, cb.z, cb.w};
    #pragma unroll
    for (int i = 0; i < 4; ++i)
      #pragma unroll
      for (int j = 0; j < 8; ++j) acc[i][j] += sa[i] * cc[j];
  }
  float* ubase = Upart + ((size_t)nt * BB + b) * MM * DD;
  #pragma unroll
  for (int i = 0; i < 4; ++i) {
    int m = m0 + i;
    if (m < MM) {
      float* ub = ubase + (size_t)m * DD;
      float4 w0 = make_float4(acc[i][0], acc[i][1], acc[i][2], acc[i][3]);
      float4 w1 = make_float4(acc[i][4], acc[i][5], acc[i][6], acc[i][7]);
      *(float4*)&ub[d0a] = w0;
      *(float4*)&ub[d0b] = w1;
    }
  }
}

// ---------------- reduce U partials ----------------
__global__ void k_Ured(const float* __restrict__ Upart, float* __restrict__ U) {
  int idx = blockIdx.x * 256 + threadIdx.x;
  if (idx >= BB * MM * DD) return;
  float s = 0.f;
  #pragma unroll
  for (int nt = 0; nt < 7; ++nt) s += Upart[(size_t)nt * BB * MM * DD + idx];
  U[idx] = s;
}

// ---------------- A,Bt = Sr @ {Q2,U}; fused final concat write (two-pass LDS) --------
__global__ __launch_bounds__(256) void k_ABtF(
    const float* __restrict__ Sr, const float* __restrict__ Q2,
    const float* __restrict__ U, const float* __restrict__ C2,
    float* __restrict__ out) {
  int b = blockIdx.x / 7, nt = blockIdx.x % 7;
  int n0 = nt * 64;
  __shared__ float Ml[MM][132];
  __shared__ float Srl[64][52];
  int tid = threadIdx.x;
  #pragma unroll
  for (int it = 0; it < 13; ++it) {
    int idx = it * 256 + tid;
    int n = idx / 52, m = idx % 52;
    Srl[n][m] = (n0 + n < NN) ? Sr[((size_t)b * NN + n0 + n) * SP + m] : 0.f;
  }
  #pragma unroll
  for (int it = 0; it < 25; ++it) {
    int idx = it * 256 + tid;
    int m = idx >> 7, d = idx & 127;
    Ml[m][d] = Q2[((size_t)b * MM + m) * DD + d];
  }
  __syncthreads();
  int nq = tid >> 4, dt = tid & 15;
  int d0a = dt * 4, d0b = 64 + dt * 4;
  float accA[4][8] = {}, accB[4][8] = {};
  for (int m = 0; m < MM; ++m) {
    float s[4];
    #pragma unroll
    for (int i = 0; i < 4; ++i) s[i] = Srl[nq * 4 + i][m];
    float4 qa = *(const float4*)&Ml[m][d0a];
    float4 qb = *(const float4*)&Ml[m][d0b];
    float qq[8] = {qa.x, qa.y, qa.z, qa.w, qb.x, qb.y, qb.z, qb.w};
    #pragma unroll
    for (int i = 0; i < 4; ++i)
      #pragma unroll
      for (int j = 0; j < 8; ++j) accA[i][j] += s[i] * qq[j];
  }
  __syncthreads();
  #pragma unroll
  for (int it = 0; it < 25; ++it) {
    int idx = it * 256 + tid;
    int m = idx >> 7, d = idx & 127;
    Ml[m][d] = U[((size_t)b * MM + m) * DD + d];
  }
  __syncthreads();
  for (int m = 0; m < MM; ++m) {
    float s[4];
    #pragma unroll
    for (int i = 0; i < 4; ++i) s[i] = Srl[nq * 4 + i][m];
    float4 ua = *(const float4*)&Ml[m][d0a];
    float4 ub = *(const float4*)&Ml[m][d0b];
    float uu[8] = {ua.x, ua.y, ua.z, ua.w, ub.x, ub.y, ub.z, ub.w};
    #pragma unroll
    for (int i = 0; i < 4; ++i)
      #pragma unroll
      for (int j = 0; j < 8; ++j) accB[i][j] += s[i] * uu[j];
  }
  #pragma unroll
  for (int i = 0; i < 4; ++i) {
    int n = n0 + nq * 4 + i;
    if (n < NN) {
      const float* c2r = C2 + ((size_t)b * NN + n) * DD;
      float4 ca = *(const float4*)&c2r[d0a];
      float4 cb = *(const float4*)&c2r[d0b];
      float cc[8] = {ca.x, ca.y, ca.z, ca.w, cb.x, cb.y, cb.z, cb.w};
      float* po = out + ((size_t)b * NN + n) * 512;
      float4 w0, w1;
      *(float4*)&po[d0a] = ca;
      *(float4*)&po[d0b] = cb;
      w0 = make_float4(accA[i][0], accA[i][1], accA[i][2], accA[i][3]);
      w1 = make_float4(accA[i][4], accA[i][5], accA[i][6], accA[i][7]);
      *(float4*)&po[128 + d0a] = w0;
      *(float4*)&po[128 + d0b] = w1;
      w0 = make_float4(cc[0]*accA[i][0], cc[1]*accA[i][1], cc[2]*accA[i][2], cc[3]*accA[i][3]);
      w1 = make_float4(cc[4]*accA[i][4], cc[5]*accA[i][5], cc[6]*accA[i][6], cc[7]*accA[i][7]);
      *(float4*)&po[256 + d0a] = w0;
      *(float4*)&po[256 + d0b] = w1;
      w0 = make_float4(cc[0]*accB[i][0], cc[1]*accB[i][1], cc[2]*accB[i][2], cc[3]*accB[i][3]);
      w1 = make_float4(cc[4]*accB[i][4], cc[5]*accB[i][5], cc[6]*accB[i][6], cc[7]*accB[i][7]);
      *(float4*)&po[384 + d0a] = w0;
      *(float4*)&po[384 + d0b] = w1;
    }
  }
}

extern "C" void kernel_launch(void* const* d_in, const int* in_sizes, int n_in,
                              void* d_out, int out_size, void* d_ws, size_t ws_size,
                              hipStream_t stream) {
  (void)in_sizes; (void)n_in; (void)out_size; (void)ws_size;
  const float* ctx   = (const float*)d_in[0];
  const float* que   = (const float*)d_in[1];
  const float* cmask = (const float*)d_in[2];
  const float* qmask = (const float*)d_in[3];
  const float* ln_g  = (const float*)d_in[4];
  const float* ln_b  = (const float*)d_in[5];
  const float* dw_w  = (const float*)d_in[6];
  const float* dw_b  = (const float*)d_in[7];
  const float* pw_w  = (const float*)d_in[8];
  const float* pw_b  = (const float*)d_in[9];
  const float* Wq    = (const float*)d_in[10];
  const float* bq    = (const float*)d_in[11];
  const float* Wk    = (const float*)d_in[12];
  const float* bk    = (const float*)d_in[13];
  const float* Wv    = (const float*)d_in[14];
  const float* bv    = (const float*)d_in[15];
  const float* Wo    = (const float*)d_in[16];
  const float* bo    = (const float*)d_in[17];
  const float* Wfc   = (const float*)d_in[18];
  const float* bfc   = (const float*)d_in[19];
  const float* cq_wc = (const float*)d_in[20];
  const float* cq_wq = (const float*)d_in[21];
  const float* cq_wm = (const float*)d_in[22];
  const float* cq_b  = (const float*)d_in[23];
  float* out = (float*)d_out;
  float* ws = (float*)d_ws;

  float* Cb   = ws;
  float* Qb   = Cb + SZ_C;
  float* t1C  = Qb + SZ_Q;
  float* t1Q  = t1C + SZ_C;
  float* t2C  = t1Q + SZ_Q;
  float* t2Q  = t2C + SZ_C;
  float* t3C  = t2Q + SZ_Q;
  float* t3Q  = t3C + SZ_C;
  float* t4C  = t3Q + SZ_Q;
  float* t4Q  = t4C + SZ_C;
  float* muB  = t4Q + SZ_Q;
  float* invB = muB + SSTAT;
  float* Wcan = invB + SSTAT;

  int totAll = SZ_C + SZ_Q;
  int nbAll = (totAll + 255) / 256;

  k_transposeW<<<(9 * 16384 + 255) / 256, 256, 0, stream>>>(pw_w, Wo, Wfc, Wq, Wk, Wv, Wcan);
  k_pe<<<nbAll, 256, 0, stream>>>(ctx, que, Cb, Qb);

  // conv layers (ping-pong Cb <-> t1C)
  const float* srcC = Cb; const float* srcQ = Qb;
  float* dstC = t1C; float* dstQ = t1Q;
  for (int i = 0; i < NC; ++i) {
    k_lnstats<<<512, 256, 0, stream>>>(srcC, srcQ, muB, invB);
    k_gemmconv<<<1024, 256, 0, stream>>>(srcC, srcQ, dstC, dstQ,
                                         dw_w + (size_t)i * DD * KW, dw_b + (size_t)i * DD,
                                         Wcan + (size_t)i * 16384, pw_b + (size_t)i * DD,
                                         muB, invB, ln_g, ln_b);
    float* tC = (float*)srcC; float* tQ = (float*)srcQ;
    srcC = dstC; srcQ = dstQ; dstC = tC; dstQ = tQ;
  }
  // after 4 layers (NC even): Cb/Qb hold encoder state
  // self-attention
  k_lnstats<<<512, 256, 0, stream>>>(Cb, Qb, muB, invB);
  k_gemmA<<<64 * 48, 256, 0, stream>>>(Cb, Qb, t1C, t1Q, t2C, t2Q, t3C, t3Q,
                                       Wcan + 6 * 16384, bq, bk, bv, muB, invB, ln_g, ln_b);
  k_attn5<<<7680, 256, 0, stream>>>(t1C, t2C, t3C, t1Q, t2Q, t3Q, cmask, qmask, t4C, t4Q);
  k_gemmB<0><<<1024, 256, 0, stream>>>(t4C, t4Q, Cb, Qb, Cb, Qb,
                                       Wcan + 4 * 16384, bo, muB, invB, ln_g, ln_b);
  // FFN
  k_lnstats<<<512, 256, 0, stream>>>(Cb, Qb, muB, invB);
  k_gemmB<1><<<1024, 256, 0, stream>>>(Cb, Qb, Cb, Qb, t1C, t1Q,
                                       Wcan + 5 * 16384, bfc, muB, invB, ln_g, ln_b);

  // ---- context-query attention ----
  float* C2    = t2C;
  float* Q2    = t2Q;
  float* S     = t3C;   // pitch SP
  float* Scb   = t4C;   // pitch SP
  float* Uu    = t3Q;
  float* cd    = t4Q;
  float* qd    = t4Q + BB * NN;
  float* Upart = t1C;   // 7*64*50*128 = 2.87M floats, fits in t1C (free after dotD)

  int totC = BB * NN * DD;
  int totQ = BB * MM * DD;
  k_transpose<<<(totC + 255) / 256, 256, 0, stream>>>(t1C, C2, NN, totC);
  k_transpose<<<(totQ + 255) / 256, 256, 0, stream>>>(t1Q, Q2, MM, totQ);
  k_dotD<<<(BB * NN + 255) / 256, 256, 0, stream>>>(t1C, cq_wc, cd, NN, BB * NN);
  k_dotD<<<(BB * MM + 255) / 256, 256, 0, stream>>>(t1Q, cq_wq, qd, MM, BB * MM);
  k_S<<<64 * 7, 256, 0, stream>>>(C2, Q2, cd, qd, cq_wm, cq_b, S);
  k_smax_col<<<BB * MM, 64, 0, stream>>>(S, cmask, Scb);
  k_smax_row<<<BB * NN, 64, 0, stream>>>(S, qmask); // S now holds S_r
  k_U<<<64 * 7, 256, 0, stream>>>(Scb, C2, Upart);
  k_Ured<<<(BB * MM * DD + 255) / 256, 256, 0, stream>>>(Upart, Uu);
  k_ABtF<<<64 * 7, 256, 0, stream>>>(S, Q2, Uu, C2, out);
}